// Round 1
// baseline (2040.098 us; speedup 1.0000x reference)
//
#include <hip/hip_runtime.h>

// Problem constants
#define NB  16384   // batch
#define MM  64      // memory slots
#define DV  64
#define DK  64
#define DQA 128
#define MD  4096    // MM*DV

typedef float  floatx4 __attribute__((ext_vector_type(4)));
typedef short  shortx8 __attribute__((ext_vector_type(8)));

static __device__ __forceinline__ unsigned short f2bf(float f) {
  union { float f; unsigned int u; } v; v.f = f;
  unsigned int r = v.u + 0x7FFFu + ((v.u >> 16) & 1u);  // RNE
  return (unsigned short)(r >> 16);
}

static __device__ __forceinline__ float sigm(float x) { return 1.0f / (1.0f + __expf(-x)); }

static __device__ __forceinline__ shortx8 load8bf(const float* p) {
  const float4* p4 = (const float4*)p;
  float4 a = p4[0];
  float4 b = p4[1];
  shortx8 r;
  r[0] = (short)f2bf(a.x); r[1] = (short)f2bf(a.y);
  r[2] = (short)f2bf(a.z); r[3] = (short)f2bf(a.w);
  r[4] = (short)f2bf(b.x); r[5] = (short)f2bf(b.y);
  r[6] = (short)f2bf(b.z); r[7] = (short)f2bf(b.w);
  return r;
}

// ---------------------------------------------------------------------------
// K1: write_weight = softmax(control_key @ memory_key^T).  One wave per row.
// ---------------------------------------------------------------------------
__global__ __launch_bounds__(256) void k_ww(const float* __restrict__ ck,
                                            const float* __restrict__ mk,
                                            float* __restrict__ ww) {
  const int t = threadIdx.x;
  const int lane = t & 63;           // memory slot m
  const int wv = t >> 6;             // 0..3
  const int b = blockIdx.x * 4 + wv;
  const float4* ck4 = (const float4*)(ck + (size_t)b * DK);
  const float4* mk4 = (const float4*)(mk + (size_t)lane * DK);
  float s = 0.f;
#pragma unroll
  for (int i = 0; i < DK / 4; ++i) {
    float4 a = ck4[i], m = mk4[i];
    s += a.x * m.x + a.y * m.y + a.z * m.z + a.w * m.w;
  }
  float mx = s;
#pragma unroll
  for (int off = 32; off; off >>= 1) mx = fmaxf(mx, __shfl_xor(mx, off, 64));
  float e = __expf(s - mx);
  float sum = e;
#pragma unroll
  for (int off = 32; off; off >>= 1) sum += __shfl_xor(sum, off, 64);
  ww[(size_t)b * MM + lane] = e / sum;
}

// ---------------------------------------------------------------------------
// K2: content0 = qa * sigmoid(memory_value @ Wc0 + bc0)
// GEMM M=16384 K=4096 N=128.  Block = 64 rows x 128 cols, 8 waves.
// Wave w: m-half (w&1)*32 (2 m-tiles), n-quarter (w>>1)*32 (2 n-tiles).
// ---------------------------------------------------------------------------
__global__ __launch_bounds__(512) void k_c0(const float* __restrict__ mv,
                                            const float* __restrict__ Wc0,
                                            const float* __restrict__ bc0,
                                            const float* __restrict__ qa,
                                            float* __restrict__ c0g) {
  __shared__ __align__(16) unsigned short WT[DQA * 72];   // [n<128][k<64 (+8 pad)]
  const int t = threadIdx.x;
  const int lane = t & 63;
  const int wv = t >> 6;
  const int quad = lane >> 4;
  const int l16 = lane & 15;
  const int mh = wv & 1;
  const int nq = wv >> 1;         // 0..3
  const int rowbase = blockIdx.x * 64;

  floatx4 acc[2][2];
#pragma unroll
  for (int i = 0; i < 2; ++i)
#pragma unroll
    for (int j = 0; j < 2; ++j) acc[i][j] = (floatx4){0.f, 0.f, 0.f, 0.f};

  for (int kc = 0; kc < MD / 64; ++kc) {
    const int kbase = kc * 64;
    // stage Wc0[kbase..kbase+64)[0..128) transposed as bf16
#pragma unroll
    for (int i = 0; i < 16; ++i) {
      int idx = t + i * 512;            // 0..8191
      int kl = idx >> 7;                // 0..63
      int n = idx & 127;
      WT[n * 72 + kl] = f2bf(Wc0[(size_t)(kbase + kl) * DQA + n]);
    }
    __syncthreads();
#pragma unroll
    for (int ks = 0; ks < 2; ++ks) {
      shortx8 afr[2];
#pragma unroll
      for (int mt = 0; mt < 2; ++mt) {
        int row = rowbase + mh * 32 + mt * 16 + l16;
        afr[mt] = load8bf(mv + (size_t)row * MD + kbase + ks * 32 + quad * 8);
      }
#pragma unroll
      for (int nt = 0; nt < 2; ++nt) {
        int col = nq * 32 + nt * 16 + l16;
        shortx8 bfr = *(const shortx8*)&WT[col * 72 + ks * 32 + quad * 8];
#pragma unroll
        for (int mt = 0; mt < 2; ++mt)
          acc[mt][nt] = __builtin_amdgcn_mfma_f32_16x16x32_bf16(afr[mt], bfr, acc[mt][nt], 0, 0, 0);
      }
    }
    __syncthreads();
  }
#pragma unroll
  for (int mt = 0; mt < 2; ++mt)
#pragma unroll
    for (int nt = 0; nt < 2; ++nt) {
      int col = nq * 32 + nt * 16 + l16;
#pragma unroll
      for (int r = 0; r < 4; ++r) {
        int row = rowbase + mh * 32 + mt * 16 + quad * 4 + r;
        float val = acc[mt][nt][r] + bc0[col];
        c0g[(size_t)row * DQA + col] = qa[(size_t)row * DQA + col] * sigm(val);
      }
    }
}

// ---------------------------------------------------------------------------
// K3: S[b, 0:192] = memory_pre @ [Wemv | Wzmv | Wamv]   (fp32 sums)
// memory_pre is recomputed chunk-by-chunk: g1 = sigmoid(c0 @ Wm1[:,chunk]+bm1),
// mp = v * g1 (in MFMA C-layout), LDS round-trip to A-layout, then MFMA.
// Block = 64 rows, 8 waves, K-chunks of 64.
// ---------------------------------------------------------------------------
__global__ __launch_bounds__(512) void k_S(const float* __restrict__ mv,
                                           const float* __restrict__ c0g,
                                           const float* __restrict__ Wm1,
                                           const float* __restrict__ bm1,
                                           const float* __restrict__ Wemv,
                                           const float* __restrict__ Wzmv,
                                           const float* __restrict__ Wamv,
                                           float* __restrict__ Sg) {
  __shared__ __align__(16) unsigned short WT1[64 * 136];   // Wm1 chunk: [n<64][k<128 (+8)]
  __shared__ __align__(16) unsigned short W3[3][64 * 72];  // [n<64][k<64 (+8)]
  __shared__ __align__(16) unsigned short MP[64 * 72];     // mp tile: [row<64][k<64 (+8)]

  const int t = threadIdx.x;
  const int lane = t & 63;
  const int wv = t >> 6;          // 0..7
  const int quad = lane >> 4;
  const int l16 = lane & 15;
  const int rowbase = blockIdx.x * 64;
  // g1-phase roles
  const int mq = wv & 3;          // rows mq*16..+15
  const int nh = (wv >> 2) * 32;  // cols nh..nh+31 (chunk-local)
  // S-phase roles
  const int mh = wv & 1;          // rows mh*32..+31
  const int nq3 = wv >> 1;        // cols nq3*48..+47 of 192

  // c0 A-fragments (K=128, 4 k-steps) held in registers for the whole kernel
  shortx8 c0fr[4];
#pragma unroll
  for (int ks = 0; ks < 4; ++ks) {
    int row = rowbase + mq * 16 + l16;
    c0fr[ks] = load8bf(c0g + (size_t)row * DQA + ks * 32 + quad * 8);
  }

  floatx4 accS[2][3];
#pragma unroll
  for (int i = 0; i < 2; ++i)
#pragma unroll
    for (int j = 0; j < 3; ++j) accS[i][j] = (floatx4){0.f, 0.f, 0.f, 0.f};

  for (int c = 0; c < MD / 64; ++c) {
    const int kb = c * 64;
    // stage Wm1[:, kb..kb+64) transposed
#pragma unroll
    for (int i = 0; i < 16; ++i) {
      int idx = t + i * 512;     // 0..8191
      int kl = idx >> 6;         // 0..127
      int n = idx & 63;
      WT1[n * 136 + kl] = f2bf(Wm1[(size_t)kl * MD + kb + n]);
    }
    // stage the three N=64 weight chunks transposed
#pragma unroll
    for (int i = 0; i < 8; ++i) {
      int idx = t + i * 512;     // 0..4095
      int kl = idx >> 6;         // 0..63
      int n = idx & 63;
      W3[0][n * 72 + kl] = f2bf(Wemv[(size_t)(kb + kl) * DV + n]);
      W3[1][n * 72 + kl] = f2bf(Wzmv[(size_t)(kb + kl) * DV + n]);
      W3[2][n * 72 + kl] = f2bf(Wamv[(size_t)(kb + kl) * DV + n]);
    }
    __syncthreads();

    // phase B: g1 chunk -> mp tile in LDS
    {
      floatx4 accG[2];
      accG[0] = (floatx4){0.f, 0.f, 0.f, 0.f};
      accG[1] = (floatx4){0.f, 0.f, 0.f, 0.f};
#pragma unroll
      for (int ks = 0; ks < 4; ++ks) {
#pragma unroll
        for (int nt = 0; nt < 2; ++nt) {
          shortx8 bfr = *(const shortx8*)&WT1[(nh + nt * 16 + l16) * 136 + ks * 32 + quad * 8];
          accG[nt] = __builtin_amdgcn_mfma_f32_16x16x32_bf16(c0fr[ks], bfr, accG[nt], 0, 0, 0);
        }
      }
#pragma unroll
      for (int nt = 0; nt < 2; ++nt) {
        int coll = nh + nt * 16 + l16;
        int colg = kb + coll;
        float bm = bm1[colg];
#pragma unroll
        for (int r = 0; r < 4; ++r) {
          int rowl = mq * 16 + quad * 4 + r;
          float g = sigm(accG[nt][r] + bm);
          float v = mv[(size_t)(rowbase + rowl) * MD + colg];
          MP[rowl * 72 + coll] = f2bf(v * g);
        }
      }
    }
    __syncthreads();

    // phase C: accS += mp @ W3 chunk
#pragma unroll
    for (int ks = 0; ks < 2; ++ks) {
      shortx8 afr[2];
#pragma unroll
      for (int mt = 0; mt < 2; ++mt)
        afr[mt] = *(const shortx8*)&MP[(mh * 32 + mt * 16 + l16) * 72 + ks * 32 + quad * 8];
#pragma unroll
      for (int nt = 0; nt < 3; ++nt) {
        int colg = nq3 * 48 + nt * 16 + l16;   // 0..191
        int arr = colg >> 6;
        int cin = colg & 63;
        shortx8 bfr = *(const shortx8*)&W3[arr][cin * 72 + ks * 32 + quad * 8];
#pragma unroll
        for (int mt = 0; mt < 2; ++mt)
          accS[mt][nt] = __builtin_amdgcn_mfma_f32_16x16x32_bf16(afr[mt], bfr, accS[mt][nt], 0, 0, 0);
      }
    }
    __syncthreads();
  }

#pragma unroll
  for (int mt = 0; mt < 2; ++mt)
#pragma unroll
    for (int nt = 0; nt < 3; ++nt) {
      int col = nq3 * 48 + nt * 16 + l16;
#pragma unroll
      for (int r = 0; r < 4; ++r) {
        int row = rowbase + mh * 32 + mt * 16 + quad * 4 + r;
        Sg[(size_t)row * 192 + col] = accS[mt][nt][r];
      }
    }
}

// ---------------------------------------------------------------------------
// K4: finalize erase / zt / add  (small GEMMs, fp32 VALU).
// Block = 4 rows x 64 cols.
// ---------------------------------------------------------------------------
__global__ __launch_bounds__(256) void k_eza(const float* __restrict__ c0g,
                                             const float* __restrict__ Sg,
                                             const float* __restrict__ We,
                                             const float* __restrict__ be,
                                             const float* __restrict__ Wz,
                                             const float* __restrict__ bz,
                                             const float* __restrict__ Wza,
                                             const float* __restrict__ bza,
                                             const float* __restrict__ bemv,
                                             const float* __restrict__ bzmv,
                                             const float* __restrict__ bamv,
                                             float* __restrict__ eg,
                                             float* __restrict__ ag) {
  __shared__ float ztl[4][64];
  const int t = threadIdx.x;
  const int j = t & 63;
  const int r = t >> 6;
  const int b = blockIdx.x * 4 + r;
  const float* c0r = c0g + (size_t)b * DQA;
  float ae = 0.f, az = 0.f;
#pragma unroll 8
  for (int k = 0; k < DQA; ++k) {
    float cv = c0r[k];
    ae += cv * We[k * DV + j];
    az += cv * Wz[k * DV + j];
  }
  const float* Sr = Sg + (size_t)b * 192;
  float zt = sigm(az + bz[j] + Sr[64 + j] + bzmv[j]);
  ztl[r][j] = zt;
  __syncthreads();
  float aa = 0.f;
#pragma unroll 8
  for (int k = 0; k < DV; ++k) aa += ztl[r][k] * Wza[k * DV + j];
  float aval = tanhf(tanhf(aa + bza[j]) + tanhf(Sr[128 + j] + bamv[j]));
  float eval = sigm(sigm(ae + be[j]) + sigm(Sr[j] + bemv[j]));
  eg[(size_t)b * DV + j] = eval;
  ag[(size_t)b * DV + j] = aval;
}

// ---------------------------------------------------------------------------
// K5: recompute g1 tile, mp = v*g1 (fp32), out = mp*(1-w*e) + w*a
// Grid (rows/64, 4096/128); block = 4 waves; wave w owns rows w*16..+15.
// ---------------------------------------------------------------------------
__global__ __launch_bounds__(256) void k_final(const float* __restrict__ mv,
                                               const float* __restrict__ c0g,
                                               const float* __restrict__ Wm1,
                                               const float* __restrict__ bm1,
                                               const float* __restrict__ ww,
                                               const float* __restrict__ eg,
                                               const float* __restrict__ ag,
                                               float* __restrict__ outp) {
  __shared__ __align__(16) unsigned short WT[128 * 136];   // [n<128][k<128 (+8)]
  const int t = threadIdx.x;
  const int lane = t & 63;
  const int wv = t >> 6;     // 0..3 -> m quarter
  const int quad = lane >> 4;
  const int l16 = lane & 15;
  const int rowbase = blockIdx.x * 64;
  const int colbase = blockIdx.y * 128;

  for (int i = 0; i < 64; ++i) {
    int idx = t + i * 256;         // 0..16383
    int kl = idx >> 7;             // 0..127
    int n = idx & 127;
    WT[n * 136 + kl] = f2bf(Wm1[(size_t)kl * MD + colbase + n]);
  }
  shortx8 c0fr[4];
#pragma unroll
  for (int ks = 0; ks < 4; ++ks) {
    int row = rowbase + wv * 16 + l16;
    c0fr[ks] = load8bf(c0g + (size_t)row * DQA + ks * 32 + quad * 8);
  }
  __syncthreads();

  floatx4 acc[8];
#pragma unroll
  for (int nt = 0; nt < 8; ++nt) acc[nt] = (floatx4){0.f, 0.f, 0.f, 0.f};
#pragma unroll
  for (int nt = 0; nt < 8; ++nt)
#pragma unroll
    for (int ks = 0; ks < 4; ++ks) {
      shortx8 bfr = *(const shortx8*)&WT[(nt * 16 + l16) * 136 + ks * 32 + quad * 8];
      acc[nt] = __builtin_amdgcn_mfma_f32_16x16x32_bf16(c0fr[ks], bfr, acc[nt], 0, 0, 0);
    }

#pragma unroll
  for (int nt = 0; nt < 8; ++nt) {
    int colg = colbase + nt * 16 + l16;
    int mi = colg >> 6;       // memory slot
    int j = colg & 63;        // dv index
    float bm = bm1[colg];
#pragma unroll
    for (int r = 0; r < 4; ++r) {
      int row = rowbase + wv * 16 + quad * 4 + r;
      float g = sigm(acc[nt][r] + bm);
      float mp = mv[(size_t)row * MD + colg] * g;
      float w = ww[(size_t)row * MM + mi];
      float e = eg[(size_t)row * DV + j];
      float a = ag[(size_t)row * DV + j];
      outp[(size_t)row * MD + colg] = mp * (1.f - w * e) + w * a;
    }
  }
}

// ---------------------------------------------------------------------------
extern "C" void kernel_launch(void* const* d_in, const int* in_sizes, int n_in,
                              void* d_out, int out_size, void* d_ws, size_t ws_size,
                              hipStream_t stream) {
  const float* ck   = (const float*)d_in[0];   // (B, DK)
  const float* qa   = (const float*)d_in[1];   // (B, DQA)
  const float* mk   = (const float*)d_in[2];   // (M, DK)
  const float* mv   = (const float*)d_in[3];   // (B, M, DV)
  const float* We   = (const float*)d_in[4];
  const float* be   = (const float*)d_in[5];
  const float* Wemv = (const float*)d_in[6];
  const float* bemv = (const float*)d_in[7];
  const float* Wza  = (const float*)d_in[8];
  const float* bza  = (const float*)d_in[9];
  const float* Wamv = (const float*)d_in[10];
  const float* bamv = (const float*)d_in[11];
  const float* Wc0  = (const float*)d_in[12];
  const float* bc0  = (const float*)d_in[13];
  const float* Wm1  = (const float*)d_in[14];
  const float* bm1  = (const float*)d_in[15];
  const float* Wz   = (const float*)d_in[16];
  const float* bz   = (const float*)d_in[17];
  const float* Wzmv = (const float*)d_in[18];
  const float* bzmv = (const float*)d_in[19];
  float* outp = (float*)d_out;

  // workspace carve (needs 32 MB): ww | c0 | S | e | a
  float* ws  = (float*)d_ws;
  float* wwp = ws;
  float* c0p = wwp + (size_t)NB * MM;
  float* Sp  = c0p + (size_t)NB * DQA;
  float* ep  = Sp + (size_t)NB * 192;
  float* ap  = ep + (size_t)NB * DV;

  k_ww<<<NB / 4, 256, 0, stream>>>(ck, mk, wwp);
  k_c0<<<NB / 64, 512, 0, stream>>>(mv, Wc0, bc0, qa, c0p);
  k_S<<<NB / 64, 512, 0, stream>>>(mv, c0p, Wm1, bm1, Wemv, Wzmv, Wamv, Sp);
  k_eza<<<NB / 4, 256, 0, stream>>>(c0p, Sp, We, be, Wz, bz, Wza, bza, bemv, bzmv, bamv, ep, ap);
  k_final<<<dim3(NB / 64, MD / 128), 256, 0, stream>>>(mv, c0p, Wm1, bm1, wwp, ep, ap, outp);
}

// Round 2
// 1145.572 us; speedup vs baseline: 1.7809x; 1.7809x over previous
//
#include <hip/hip_runtime.h>

// Problem constants
#define NB  16384   // batch
#define MM  64      // memory slots
#define DV  64
#define DK  64
#define DQA 128
#define MD  4096    // MM*DV

typedef float  floatx4 __attribute__((ext_vector_type(4)));
typedef short  shortx8 __attribute__((ext_vector_type(8)));

static __device__ __forceinline__ unsigned short f2bf(float f) {
  union { float f; unsigned int u; } v; v.f = f;
  unsigned int r = v.u + 0x7FFFu + ((v.u >> 16) & 1u);  // RNE
  return (unsigned short)(r >> 16);
}
static __device__ __forceinline__ float bf2f(unsigned short u) {
  union { unsigned int u; float f; } v; v.u = (unsigned int)u << 16; return v.f;
}
static __device__ __forceinline__ float sigm(float x) { return 1.0f / (1.0f + __expf(-x)); }

static __device__ __forceinline__ shortx8 load8bf(const float* p) {
  const float4* p4 = (const float4*)p;
  float4 a = p4[0];
  float4 b = p4[1];
  shortx8 r;
  r[0] = (short)f2bf(a.x); r[1] = (short)f2bf(a.y);
  r[2] = (short)f2bf(a.z); r[3] = (short)f2bf(a.w);
  r[4] = (short)f2bf(b.x); r[5] = (short)f2bf(b.y);
  r[6] = (short)f2bf(b.z); r[7] = (short)f2bf(b.w);
  return r;
}

// ---------------------------------------------------------------------------
// k_tr: transpose+convert  src fp32 [K][N] (row-major, ld=N)  ->  dst bf16 [N][K']
// grid (K/64, N/64).  dstld = dst row stride in elements.
// ---------------------------------------------------------------------------
__global__ __launch_bounds__(256) void k_tr(const float* __restrict__ src,
                                            unsigned short* __restrict__ dst,
                                            int N, int dstld) {
  __shared__ unsigned short T[64 * 72];
  const int k0 = blockIdx.x * 64, n0 = blockIdx.y * 64;
  const int t = threadIdx.x;
#pragma unroll
  for (int i = 0; i < 16; ++i) {
    int idx = t + i * 256, kl = idx >> 6, nl = idx & 63;
    T[kl * 72 + nl] = f2bf(src[(size_t)(k0 + kl) * N + n0 + nl]);
  }
  __syncthreads();
#pragma unroll
  for (int i = 0; i < 16; ++i) {
    int idx = t + i * 256, nl = idx >> 6, kl = idx & 63;
    dst[(size_t)(n0 + nl) * dstld + k0 + kl] = T[kl * 72 + nl];
  }
}

// ---------------------------------------------------------------------------
// K1: write_weight = softmax(control_key @ memory_key^T).  One wave per row.
// ---------------------------------------------------------------------------
__global__ __launch_bounds__(256) void k_ww(const float* __restrict__ ck,
                                            const float* __restrict__ mk,
                                            float* __restrict__ ww) {
  const int t = threadIdx.x;
  const int lane = t & 63;
  const int wv = t >> 6;
  const int b = blockIdx.x * 4 + wv;
  const float4* ck4 = (const float4*)(ck + (size_t)b * DK);
  const float4* mk4 = (const float4*)(mk + (size_t)lane * DK);
  float s = 0.f;
#pragma unroll
  for (int i = 0; i < DK / 4; ++i) {
    float4 a = ck4[i], m = mk4[i];
    s += a.x * m.x + a.y * m.y + a.z * m.z + a.w * m.w;
  }
  float mx = s;
#pragma unroll
  for (int off = 32; off; off >>= 1) mx = fmaxf(mx, __shfl_xor(mx, off, 64));
  float e = __expf(s - mx);
  float sum = e;
#pragma unroll
  for (int off = 32; off; off >>= 1) sum += __shfl_xor(sum, off, 64);
  ww[(size_t)b * MM + lane] = e / sum;
}

// ---------------------------------------------------------------------------
// K2: c0 = qa * sigmoid(mv @ Wc0 + bc0), stored bf16.
// Block = 32 rows x 128 cols, 4 waves: wave (mh=wv&1) rows mh*16, (nq2=wv>>1) cols nq2*64.
// ---------------------------------------------------------------------------
__global__ __launch_bounds__(256) void k_c0(const float* __restrict__ mv,
                                            const unsigned short* __restrict__ WcT,
                                            const float* __restrict__ bc0,
                                            const float* __restrict__ qa,
                                            unsigned short* __restrict__ c0p) {
  __shared__ __align__(16) unsigned short WB[DQA * 136];   // [n<128][k<128 +8]
  const int t = threadIdx.x, lane = t & 63, wv = t >> 6;
  const int quad = lane >> 4, l16 = lane & 15;
  const int mh = wv & 1, nq2 = wv >> 1;
  const int rowbase = blockIdx.x * 32;
  const int arow = rowbase + mh * 16 + l16;

  floatx4 acc[4];
#pragma unroll
  for (int nt = 0; nt < 4; ++nt) acc[nt] = (floatx4){0.f, 0.f, 0.f, 0.f};

  for (int kc = 0; kc < MD / 128; ++kc) {
    const int kb = kc * 128;
    // A fragments first (global latency overlaps staging)
    shortx8 afr[4];
#pragma unroll
    for (int ks = 0; ks < 4; ++ks)
      afr[ks] = load8bf(mv + (size_t)arow * MD + kb + ks * 32 + quad * 8);
    // stage WcT[:, kb..kb+128) as [n][k] bf16 (pure 16B copies)
#pragma unroll
    for (int i = 0; i < 8; ++i) {
      int idx = t + i * 256;     // 0..2047
      int n = idx >> 4, kbk = idx & 15;
      *(shortx8*)&WB[n * 136 + kbk * 8] =
          *(const shortx8*)(WcT + (size_t)n * MD + kb + kbk * 8);
    }
    __syncthreads();
#pragma unroll
    for (int nt = 0; nt < 4; ++nt)
#pragma unroll
      for (int ks = 0; ks < 4; ++ks) {
        shortx8 bfr = *(const shortx8*)&WB[(nq2 * 64 + nt * 16 + l16) * 136 + ks * 32 + quad * 8];
        acc[nt] = __builtin_amdgcn_mfma_f32_16x16x32_bf16(afr[ks], bfr, acc[nt], 0, 0, 0);
      }
    __syncthreads();
  }
#pragma unroll
  for (int nt = 0; nt < 4; ++nt) {
    int col = nq2 * 64 + nt * 16 + l16;
    float b = bc0[col];
#pragma unroll
    for (int r = 0; r < 4; ++r) {
      int row = rowbase + mh * 16 + quad * 4 + r;
      float val = qa[(size_t)row * DQA + col] * sigm(acc[nt][r] + b);
      c0p[(size_t)row * DQA + col] = f2bf(val);
    }
  }
}

// ---------------------------------------------------------------------------
// K3: gate1 chunk via MFMA, mp = mv * g1 (fp32) written into d_out.
// Grid (NB/64, MD/128), 256 thr (4 waves, wave wv rows wv*16, all 128 cols).
// ---------------------------------------------------------------------------
__global__ __launch_bounds__(256) void k_g1mp(const float* __restrict__ mv,
                                              const unsigned short* __restrict__ c0p,
                                              const unsigned short* __restrict__ Wm1T,
                                              const float* __restrict__ bm1,
                                              float* __restrict__ mp) {
  __shared__ __align__(16) unsigned short WB[128 * 136];   // [n<128][k<128 +8]
  const int t = threadIdx.x, lane = t & 63, wv = t >> 6;
  const int quad = lane >> 4, l16 = lane & 15;
  const int rowbase = blockIdx.x * 64;
  const int colbase = blockIdx.y * 128;

  // c0 A-fragments (full K=128)
  shortx8 c0fr[4];
#pragma unroll
  for (int ks = 0; ks < 4; ++ks)
    c0fr[ks] = *(const shortx8*)(c0p + (size_t)(rowbase + wv * 16 + l16) * DQA + ks * 32 + quad * 8);

  // stage Wm1T rows [colbase..colbase+128), full K=128
#pragma unroll
  for (int i = 0; i < 8; ++i) {
    int idx = t + i * 256;
    int n = idx >> 4, kbk = idx & 15;
    *(shortx8*)&WB[n * 136 + kbk * 8] =
        *(const shortx8*)(Wm1T + (size_t)(colbase + n) * DQA + kbk * 8);
  }
  __syncthreads();

  floatx4 acc[8];
#pragma unroll
  for (int nt = 0; nt < 8; ++nt) acc[nt] = (floatx4){0.f, 0.f, 0.f, 0.f};
#pragma unroll
  for (int nt = 0; nt < 8; ++nt)
#pragma unroll
    for (int ks = 0; ks < 4; ++ks) {
      shortx8 bfr = *(const shortx8*)&WB[(nt * 16 + l16) * 136 + ks * 32 + quad * 8];
      acc[nt] = __builtin_amdgcn_mfma_f32_16x16x32_bf16(c0fr[ks], bfr, acc[nt], 0, 0, 0);
    }

#pragma unroll
  for (int nt = 0; nt < 8; ++nt) {
    int colg = colbase + nt * 16 + l16;
    float b = bm1[colg];
#pragma unroll
    for (int r = 0; r < 4; ++r) {
      int row = rowbase + wv * 16 + quad * 4 + r;
      float g = sigm(acc[nt][r] + b);
      mp[(size_t)row * MD + colg] = mv[(size_t)row * MD + colg] * g;
    }
  }
}

// ---------------------------------------------------------------------------
// K4: S[16384 x 192] = mp @ [WemvT|WzmvT|WamvT]^T   (mp fp32 in d_out)
// Block = 32 rows x 192 cols, 4 waves: rows (wv&1)*16, cols (wv>>1)*96 (6 n-tiles).
// ---------------------------------------------------------------------------
__global__ __launch_bounds__(256) void k_S(const float* __restrict__ mp,
                                           const unsigned short* __restrict__ W3T,
                                           float* __restrict__ Sg) {
  __shared__ __align__(16) unsigned short WB[192 * 136];   // [n<192][k<128 +8]
  const int t = threadIdx.x, lane = t & 63, wv = t >> 6;
  const int quad = lane >> 4, l16 = lane & 15;
  const int mh = wv & 1, nh2 = wv >> 1;
  const int rowbase = blockIdx.x * 32;
  const int arow = rowbase + mh * 16 + l16;

  floatx4 acc[6];
#pragma unroll
  for (int nt = 0; nt < 6; ++nt) acc[nt] = (floatx4){0.f, 0.f, 0.f, 0.f};

  for (int kc = 0; kc < MD / 128; ++kc) {
    const int kb = kc * 128;
    shortx8 afr[4];
#pragma unroll
    for (int ks = 0; ks < 4; ++ks)
      afr[ks] = load8bf(mp + (size_t)arow * MD + kb + ks * 32 + quad * 8);
#pragma unroll
    for (int i = 0; i < 12; ++i) {
      int idx = t + i * 256;     // 0..3071
      int n = idx >> 4, kbk = idx & 15;
      *(shortx8*)&WB[n * 136 + kbk * 8] =
          *(const shortx8*)(W3T + (size_t)n * MD + kb + kbk * 8);
    }
    __syncthreads();
#pragma unroll
    for (int nt = 0; nt < 6; ++nt)
#pragma unroll
      for (int ks = 0; ks < 4; ++ks) {
        shortx8 bfr = *(const shortx8*)&WB[(nh2 * 96 + nt * 16 + l16) * 136 + ks * 32 + quad * 8];
        acc[nt] = __builtin_amdgcn_mfma_f32_16x16x32_bf16(afr[ks], bfr, acc[nt], 0, 0, 0);
      }
    __syncthreads();
  }
#pragma unroll
  for (int nt = 0; nt < 6; ++nt) {
    int col = nh2 * 96 + nt * 16 + l16;
#pragma unroll
    for (int r = 0; r < 4; ++r) {
      int row = rowbase + mh * 16 + quad * 4 + r;
      Sg[(size_t)row * 192 + col] = acc[nt][r];
    }
  }
}

// ---------------------------------------------------------------------------
// K5: finalize erase / zt / add  (small GEMMs, fp32 VALU).  Block = 4 rows x 64.
// ---------------------------------------------------------------------------
__global__ __launch_bounds__(256) void k_eza(const unsigned short* __restrict__ c0p,
                                             const float* __restrict__ Sg,
                                             const float* __restrict__ We,
                                             const float* __restrict__ be,
                                             const float* __restrict__ Wz,
                                             const float* __restrict__ bz,
                                             const float* __restrict__ Wza,
                                             const float* __restrict__ bza,
                                             const float* __restrict__ bemv,
                                             const float* __restrict__ bzmv,
                                             const float* __restrict__ bamv,
                                             float* __restrict__ eg,
                                             float* __restrict__ ag) {
  __shared__ float ztl[4][64];
  const int t = threadIdx.x;
  const int j = t & 63;
  const int r = t >> 6;
  const int b = blockIdx.x * 4 + r;
  const unsigned short* c0r = c0p + (size_t)b * DQA;
  float ae = 0.f, az = 0.f;
#pragma unroll 8
  for (int k = 0; k < DQA; ++k) {
    float cv = bf2f(c0r[k]);
    ae += cv * We[k * DV + j];
    az += cv * Wz[k * DV + j];
  }
  const float* Sr = Sg + (size_t)b * 192;
  float zt = sigm(az + bz[j] + Sr[64 + j] + bzmv[j]);
  ztl[r][j] = zt;
  __syncthreads();
  float aa = 0.f;
#pragma unroll 8
  for (int k = 0; k < DV; ++k) aa += ztl[r][k] * Wza[k * DV + j];
  float aval = tanhf(tanhf(aa + bza[j]) + tanhf(Sr[128 + j] + bamv[j]));
  float eval = sigm(sigm(ae + be[j]) + sigm(Sr[j] + bemv[j]));
  eg[(size_t)b * DV + j] = eval;
  ag[(size_t)b * DV + j] = aval;
}

// ---------------------------------------------------------------------------
// K6: in-place elementwise on d_out:  out = mp*(1 - w*e) + w*a
// ---------------------------------------------------------------------------
__global__ __launch_bounds__(256) void k_final(float* __restrict__ mp,
                                               const float* __restrict__ ww,
                                               const float* __restrict__ eg,
                                               const float* __restrict__ ag) {
  const size_t idx8 = ((size_t)blockIdx.x * 256 + threadIdx.x) * 8;
  const int row = (int)(idx8 >> 12);
  const int colg = (int)(idx8 & 4095);
  const int mi = colg >> 6, j = colg & 63;
  const float w = ww[(size_t)row * MM + mi];
  const float4 e0 = *(const float4*)(eg + (size_t)row * DV + j);
  const float4 e1 = *(const float4*)(eg + (size_t)row * DV + j + 4);
  const float4 a0 = *(const float4*)(ag + (size_t)row * DV + j);
  const float4 a1 = *(const float4*)(ag + (size_t)row * DV + j + 4);
  float4 m0 = *(const float4*)(mp + idx8);
  float4 m1 = *(const float4*)(mp + idx8 + 4);
  m0.x = m0.x * (1.f - w * e0.x) + w * a0.x;
  m0.y = m0.y * (1.f - w * e0.y) + w * a0.y;
  m0.z = m0.z * (1.f - w * e0.z) + w * a0.z;
  m0.w = m0.w * (1.f - w * e0.w) + w * a0.w;
  m1.x = m1.x * (1.f - w * e1.x) + w * a1.x;
  m1.y = m1.y * (1.f - w * e1.y) + w * a1.y;
  m1.z = m1.z * (1.f - w * e1.z) + w * a1.z;
  m1.w = m1.w * (1.f - w * e1.w) + w * a1.w;
  *(float4*)(mp + idx8) = m0;
  *(float4*)(mp + idx8 + 4) = m1;
}

// ---------------------------------------------------------------------------
extern "C" void kernel_launch(void* const* d_in, const int* in_sizes, int n_in,
                              void* d_out, int out_size, void* d_ws, size_t ws_size,
                              hipStream_t stream) {
  const float* ck   = (const float*)d_in[0];
  const float* qa   = (const float*)d_in[1];
  const float* mk   = (const float*)d_in[2];
  const float* mv   = (const float*)d_in[3];
  const float* We   = (const float*)d_in[4];
  const float* be   = (const float*)d_in[5];
  const float* Wemv = (const float*)d_in[6];
  const float* bemv = (const float*)d_in[7];
  const float* Wza  = (const float*)d_in[8];
  const float* bza  = (const float*)d_in[9];
  const float* Wamv = (const float*)d_in[10];
  const float* bamv = (const float*)d_in[11];
  const float* Wc0  = (const float*)d_in[12];
  const float* bc0  = (const float*)d_in[13];
  const float* Wm1  = (const float*)d_in[14];
  const float* bm1  = (const float*)d_in[15];
  const float* Wz   = (const float*)d_in[16];
  const float* bz   = (const float*)d_in[17];
  const float* Wzmv = (const float*)d_in[18];
  const float* bzmv = (const float*)d_in[19];
  float* outp = (float*)d_out;

  // workspace carve (~32.1 MB)
  char* base = (char*)d_ws;
  float* wwp = (float*)base;                      base += (size_t)NB * MM * 4;
  unsigned short* c0p = (unsigned short*)base;    base += (size_t)NB * DQA * 2;
  float* Sp = (float*)base;                       base += (size_t)NB * 192 * 4;
  float* ep = (float*)base;                       base += (size_t)NB * DV * 4;
  float* ap = (float*)base;                       base += (size_t)NB * DV * 4;
  unsigned short* WcT  = (unsigned short*)base;   base += (size_t)DQA * MD * 2;
  unsigned short* Wm1T = (unsigned short*)base;   base += (size_t)MD * DQA * 2;
  unsigned short* W3T  = (unsigned short*)base;   base += (size_t)192 * MD * 2;

  // weight prep (bf16 + transpose)
  k_tr<<<dim3(MD / 64, DQA / 64), 256, 0, stream>>>(Wc0, WcT, DQA, MD);
  k_tr<<<dim3(DQA / 64, MD / 64), 256, 0, stream>>>(Wm1, Wm1T, MD, DQA);
  k_tr<<<dim3(MD / 64, 1), 256, 0, stream>>>(Wemv, W3T, DV, MD);
  k_tr<<<dim3(MD / 64, 1), 256, 0, stream>>>(Wzmv, W3T + (size_t)64 * MD, DV, MD);
  k_tr<<<dim3(MD / 64, 1), 256, 0, stream>>>(Wamv, W3T + (size_t)128 * MD, DV, MD);

  k_ww<<<NB / 4, 256, 0, stream>>>(ck, mk, wwp);
  k_c0<<<NB / 32, 256, 0, stream>>>(mv, WcT, bc0, qa, c0p);
  k_g1mp<<<dim3(NB / 64, MD / 128), 256, 0, stream>>>(mv, c0p, Wm1T, bm1, outp);
  k_S<<<NB / 32, 256, 0, stream>>>(outp, W3T, Sp);
  k_eza<<<NB / 4, 256, 0, stream>>>(c0p, Sp, We, be, Wz, bz, Wza, bza, bemv, bzmv, bamv, ep, ap);
  k_final<<<(NB * MD / 8) / 256, 256, 0, stream>>>(outp, wwp, ep, ap);
}